// Round 1
// baseline (1281.720 us; speedup 1.0000x reference)
//
#include <hip/hip_runtime.h>
#include <hip/hip_bf16.h>

// LatentODE: 819200 independent rows, each a tiny fused MLP + 10 Euler steps.
// Round 1: fp32, one thread per row, weights broadcast from LDS.

__device__ __forceinline__ float tanh_fast(float v) {
    // tanh(v) = 1 - 2/(exp2(2*log2(e)*v) + 1); stable at +-inf
    float e = __builtin_exp2f(v * 2.8853900817779268f);
    return 1.0f - 2.0f * __builtin_amdgcn_rcpf(e + 1.0f);
}

struct alignas(16) SW {
    float ow1T[50][40];   // [hidden_i][xz_k]  (xz = concat(z[32], x[8]))
    float ow2s[50][32];
    float jw1T[50][8];
    float jw2s[50][32];
    float mw1T[32][32];
    float sw1T[32][32];
    float jb1s[50];
    float ob1s[50];
    float jb2s[32];
    float ob2s[32];
    float mb1s[32];
    float sb1s[32];
    float mw2s[32];
    float sw2s[32];
    float mb2s;
    float sb2s;
};

__global__ __launch_bounds__(256) void latent_ode_kernel(
    const float* __restrict__ dt, const float* __restrict__ x,
    const float* __restrict__ jw1, const float* __restrict__ jb1,
    const float* __restrict__ jw2, const float* __restrict__ jb2,
    const float* __restrict__ ow1, const float* __restrict__ ob1,
    const float* __restrict__ ow2, const float* __restrict__ ob2,
    const float* __restrict__ mw1, const float* __restrict__ mb1,
    const float* __restrict__ mw2, const float* __restrict__ mb2,
    const float* __restrict__ sw1, const float* __restrict__ sb1,
    const float* __restrict__ sw2, const float* __restrict__ sb2,
    float* __restrict__ out, int rows)
{
    __shared__ SW s;
    const int tid = threadIdx.x;

    // ---- stage weights to LDS (transpose where inner loop needs rows) ----
    for (int idx = tid; idx < 50 * 40; idx += 256) {
        int i = idx / 40, k = idx % 40;
        s.ow1T[i][k] = ow1[k * 50 + i];
    }
    for (int idx = tid; idx < 50 * 32; idx += 256) s.ow2s[idx / 32][idx % 32] = ow2[idx];
    for (int idx = tid; idx < 50 * 8; idx += 256) {
        int i = idx / 8, k = idx % 8;
        s.jw1T[i][k] = jw1[k * 50 + i];
    }
    for (int idx = tid; idx < 50 * 32; idx += 256) s.jw2s[idx / 32][idx % 32] = jw2[idx];
    for (int idx = tid; idx < 32 * 32; idx += 256) {
        int i = idx / 32, k = idx % 32;
        s.mw1T[i][k] = mw1[k * 32 + i];
        s.sw1T[i][k] = sw1[k * 32 + i];
    }
    if (tid < 50) { s.jb1s[tid] = jb1[tid]; s.ob1s[tid] = ob1[tid]; }
    if (tid < 32) {
        s.jb2s[tid] = jb2[tid]; s.ob2s[tid] = ob2[tid];
        s.mb1s[tid] = mb1[tid]; s.sb1s[tid] = sb1[tid];
        s.mw2s[tid] = mw2[tid]; s.sw2s[tid] = sw2[tid];
    }
    if (tid == 0) { s.mb2s = mb2[0]; s.sb2s = sb2[0]; }
    __syncthreads();

    const int r = blockIdx.x * 256 + tid;
    if (r >= rows) return;

    const float dti = dt[2 * r + 1] - dt[2 * r];
    const float scale = dti * (1.0f / 240.0f);  // dti * (1/24) * 0.1

    float xv[8];
    {
        const float4* xp = reinterpret_cast<const float4*>(x + (size_t)r * 8);
        float4 a = xp[0], b = xp[1];
        xv[0] = a.x; xv[1] = a.y; xv[2] = a.z; xv[3] = a.w;
        xv[4] = b.x; xv[5] = b.y; xv[6] = b.z; xv[7] = b.w;
    }

    // ---- jumpNN: z0 = tanh(tanh(x@jw1+jb1)@jw2+jb2) ----
    float z[32];
    {
        float acc[32];
        #pragma unroll
        for (int j = 0; j < 32; ++j) acc[j] = s.jb2s[j];
        for (int i = 0; i < 50; ++i) {
            float h = s.jb1s[i];
            #pragma unroll
            for (int k = 0; k < 8; ++k) h += xv[k] * s.jw1T[i][k];
            h = tanh_fast(h);
            #pragma unroll
            for (int j = 0; j < 32; ++j) acc[j] += h * s.jw2s[i][j];
        }
        #pragma unroll
        for (int j = 0; j < 32; ++j) z[j] = tanh_fast(acc[j]);
    }

    // ---- 10 Euler steps: f = tanh(relu([z,x]@ow1+ob1)@ow2+ob2); z += scale*f ----
    for (int t = 0; t < 10; ++t) {
        float f[32];
        #pragma unroll
        for (int j = 0; j < 32; ++j) f[j] = s.ob2s[j];
        for (int i = 0; i < 50; ++i) {
            float h = s.ob1s[i];
            #pragma unroll
            for (int k = 0; k < 32; ++k) h += z[k] * s.ow1T[i][k];
            #pragma unroll
            for (int k = 0; k < 8; ++k) h += xv[k] * s.ow1T[i][32 + k];
            h = fmaxf(h, 0.0f);
            #pragma unroll
            for (int j = 0; j < 32; ++j) f[j] += h * s.ow2s[i][j];
        }
        #pragma unroll
        for (int j = 0; j < 32; ++j) z[j] += scale * tanh_fast(f[j]);
    }

    // ---- heads ----
    float accm = s.mb2s;
    float accs = s.sb2s;
    for (int i = 0; i < 32; ++i) {
        float hm = s.mb1s[i];
        float hs = s.sb1s[i];
        #pragma unroll
        for (int k = 0; k < 32; ++k) {
            hm += z[k] * s.mw1T[i][k];
            hs += z[k] * s.sw1T[i][k];
        }
        accm += tanh_fast(hm) * s.mw2s[i];
        accs += tanh_fast(hs) * s.sw2s[i];
    }
    out[r] = accm;
    // softplus, numerically stable
    float v = accs;
    out[rows + r] = fmaxf(v, 0.0f) +
        0.69314718055994531f * __builtin_log2f(1.0f + __builtin_exp2f(-fabsf(v) * 1.4426950408889634f));
}

extern "C" void kernel_launch(void* const* d_in, const int* in_sizes, int n_in,
                              void* d_out, int out_size, void* d_ws, size_t ws_size,
                              hipStream_t stream) {
    const float* dt  = (const float*)d_in[0];
    const float* x   = (const float*)d_in[1];
    const float* jw1 = (const float*)d_in[2];
    const float* jb1 = (const float*)d_in[3];
    const float* jw2 = (const float*)d_in[4];
    const float* jb2 = (const float*)d_in[5];
    const float* ow1 = (const float*)d_in[6];
    const float* ob1 = (const float*)d_in[7];
    const float* ow2 = (const float*)d_in[8];
    const float* ob2 = (const float*)d_in[9];
    const float* mw1 = (const float*)d_in[10];
    const float* mb1 = (const float*)d_in[11];
    const float* mw2 = (const float*)d_in[12];
    const float* mb2 = (const float*)d_in[13];
    const float* sw1 = (const float*)d_in[14];
    const float* sb1 = (const float*)d_in[15];
    const float* sw2 = (const float*)d_in[16];
    const float* sb2 = (const float*)d_in[17];
    float* out = (float*)d_out;

    const int rows = in_sizes[1] / 8;  // B*T = 819200
    const int grid = (rows + 255) / 256;
    hipLaunchKernelGGL(latent_ode_kernel, dim3(grid), dim3(256), 0, stream,
                       dt, x, jw1, jb1, jw2, jb2, ow1, ob1, ow2, ob2,
                       mw1, mb1, mw2, mb2, sw1, sb1, sw2, sb2, out, rows);
}

// Round 2
// 310.425 us; speedup vs baseline: 4.1289x; 4.1289x over previous
//
#include <hip/hip_runtime.h>
#include <hip/hip_bf16.h>

// LatentODE round 2: bf16 MFMA formulation.
// One wave per 16-row tile (grid-stride). Weights preloaded into registers as
// B-fragments. z kept in registers in MFMA D-layout (f32 master). LDS (wave-
// private, XOR-swizzled) only for the D-layout -> A-fragment layout shuffle.

typedef __attribute__((ext_vector_type(8))) short short8;
typedef __attribute__((ext_vector_type(4))) float f32x4;
typedef unsigned short ushort_t;
typedef unsigned int uint_t;

__device__ __forceinline__ float tanh_fast(float v) {
    float e = __builtin_exp2f(v * 2.8853900817779268f);
    return 1.0f - 2.0f * __builtin_amdgcn_rcpf(e + 1.0f);
}

__device__ __forceinline__ ushort_t bf16_rne(float f) {
    union { float f; uint_t u; } x; x.f = f;
    uint_t u = x.u;
    u += 0x7FFFu + ((u >> 16) & 1u);
    return (ushort_t)(u >> 16);
}

// swizzled element index into a [16][64] bf16 LDS tile (row stride 128B).
// XOR block index (8-elem granule) by (m&7)^(m>>3): b128 reads 2-way max,
// b16 scatter writes ~2-way.
__device__ __forceinline__ int swz(int m, int col) {
    int blk = ((m & 7) ^ (m >> 3));
    return m * 64 + (col ^ (blk << 3));
}

__device__ __forceinline__ f32x4 mfma16(short8 a, short8 b, f32x4 c) {
    return __builtin_amdgcn_mfma_f32_16x16x32_bf16(a, b, c, 0, 0, 0);
}

// Build one B-fragment (lane: n = 16*t + (lane&15), k = 32*ks + 8*(lane>>4)+j)
template <typename F>
__device__ __forceinline__ short8 load_frag(F getv, int g, int c, int ks, int t) {
    short8 r;
    #pragma unroll
    for (int j = 0; j < 8; ++j) {
        int k = 32 * ks + 8 * g + j;
        int n = 16 * t + c;
        r[j] = (short)bf16_rne(getv(k, n));
    }
    return r;
}

__global__ __launch_bounds__(256, 2) void latent_ode_mfma(
    const float* __restrict__ dt, const float* __restrict__ x,
    const float* __restrict__ jw1, const float* __restrict__ jb1,
    const float* __restrict__ jw2, const float* __restrict__ jb2,
    const float* __restrict__ ow1, const float* __restrict__ ob1,
    const float* __restrict__ ow2, const float* __restrict__ ob2,
    const float* __restrict__ mw1, const float* __restrict__ mb1,
    const float* __restrict__ mw2, const float* __restrict__ mb2,
    const float* __restrict__ sw1, const float* __restrict__ sb1,
    const float* __restrict__ sw2, const float* __restrict__ sb2,
    float* __restrict__ out, int rows)
{
    __shared__ __align__(16) ushort_t lds_xz[4][16 * 64];
    __shared__ __align__(16) ushort_t lds_h[4][16 * 64];

    const int tid = threadIdx.x;
    const int w = tid >> 6, lane = tid & 63;
    const int g = lane >> 4, c = lane & 15;
    ushort_t* XZ = lds_xz[w];
    ushort_t* HB = lds_h[w];

    // zero xz pad cols 40..63 once (wave-private; pads never rewritten)
    for (int e = lane; e < 16 * 24; e += 64) {
        int m = e / 24, col = 40 + (e % 24);
        XZ[swz(m, col)] = 0;
    }

    // ---- weight fragments (stay in VGPRs for the whole kernel) ----
    auto ldJ1 = [&](int k, int n) -> float { return (k < 8 && n < 50) ? jw1[k * 50 + n] : 0.0f; };
    auto ldJ2 = [&](int k, int n) -> float { return (k < 50) ? jw2[k * 32 + n] : 0.0f; };
    auto ldO1 = [&](int k, int n) -> float { return (k < 40 && n < 50) ? ow1[k * 50 + n] : 0.0f; };
    auto ldO2 = [&](int k, int n) -> float { return (k < 50) ? ow2[k * 32 + n] : 0.0f; };
    auto ldH1 = [&](int k, int n) -> float { return (n < 32) ? mw1[k * 32 + n] : sw1[k * 32 + (n - 32)]; };
    auto ldH2 = [&](int k, int n) -> float {
        if (n == 0) return (k < 32) ? mw2[k] : 0.0f;
        if (n == 1) return (k >= 32 && k < 64) ? sw2[k - 32] : 0.0f;
        return 0.0f;
    };

    short8 jw1f[4], hw1f[4], hw2f[2];
    short8 jw2f[2][2], ow2f[2][2], ow1f[4][2];
    #pragma unroll
    for (int t = 0; t < 4; ++t) {
        jw1f[t] = load_frag(ldJ1, g, c, 0, t);
        hw1f[t] = load_frag(ldH1, g, c, 0, t);
        ow1f[t][0] = load_frag(ldO1, g, c, 0, t);
        ow1f[t][1] = load_frag(ldO1, g, c, 1, t);
    }
    #pragma unroll
    for (int t = 0; t < 2; ++t) {
        jw2f[t][0] = load_frag(ldJ2, g, c, 0, t);
        jw2f[t][1] = load_frag(ldJ2, g, c, 1, t);
        ow2f[t][0] = load_frag(ldO2, g, c, 0, t);
        ow2f[t][1] = load_frag(ldO2, g, c, 1, t);
        hw2f[t] = load_frag(ldH2, g, c, t, 0);
    }

    // ---- per-lane biases (col = 16t+c) ----
    float jb1b[4], ob1b[4], hb1b[4], jb2b[2], ob2b[2];
    #pragma unroll
    for (int t = 0; t < 4; ++t) {
        int n = 16 * t + c;
        jb1b[t] = (n < 50) ? jb1[n] : 0.0f;
        ob1b[t] = (n < 50) ? ob1[n] : 0.0f;
        hb1b[t] = (t < 2) ? mb1[n] : sb1[n - 32];
    }
    #pragma unroll
    for (int t = 0; t < 2; ++t) {
        jb2b[t] = jb2[16 * t + c];
        ob2b[t] = ob2[16 * t + c];
    }
    const float mb2v = mb2[0], sb2v = sb2[0];

    const int ntiles = rows >> 4;
    const int nwaves = (gridDim.x * blockDim.x) >> 6;
    const int wgid = (blockIdx.x * blockDim.x + tid) >> 6;

    for (int tile = wgid; tile < ntiles; tile += nwaves) {
        const int row0 = tile << 4;

        // x -> xz cols 32..39 (bf16)
        {
            int m = lane >> 2, ci = (lane & 3) * 2;
            const float2 xv = *reinterpret_cast<const float2*>(&x[(size_t)(row0 + m) * 8 + ci]);
            int idx = swz(m, 32 + ci);
            XZ[idx] = bf16_rne(xv.x);
            XZ[idx + 1] = bf16_rne(xv.y);
        }
        // per-row scale (rows 4g+r)
        f32x4 sv;
        #pragma unroll
        for (int r = 0; r < 4; ++r) {
            const float2 d = *reinterpret_cast<const float2*>(&dt[(size_t)(row0 + 4 * g + r) * 2]);
            sv[r] = (d.y - d.x) * (1.0f / 240.0f);
        }

        // ---- jumpNN layer1: h = tanh(x @ jw1 + jb1) ----
        {
            short8 a0 = *reinterpret_cast<const short8*>(&XZ[swz(c, 32 + 8 * g)]);
            #pragma unroll
            for (int t = 0; t < 4; ++t) {
                f32x4 a = {jb1b[t], jb1b[t], jb1b[t], jb1b[t]};
                a = mfma16(a0, jw1f[t], a);
                #pragma unroll
                for (int r = 0; r < 4; ++r)
                    HB[swz(4 * g + r, 16 * t + c)] = bf16_rne(tanh_fast(a[r]));
            }
        }
        // ---- jumpNN layer2: z0 = tanh(h @ jw2 + jb2) ----
        f32x4 z[2];
        {
            short8 h0 = *reinterpret_cast<const short8*>(&HB[swz(c, 8 * g)]);
            short8 h1 = *reinterpret_cast<const short8*>(&HB[swz(c, 32 + 8 * g)]);
            #pragma unroll
            for (int t = 0; t < 2; ++t) {
                f32x4 a = {jb2b[t], jb2b[t], jb2b[t], jb2b[t]};
                a = mfma16(h0, jw2f[t][0], a);
                a = mfma16(h1, jw2f[t][1], a);
                #pragma unroll
                for (int r = 0; r < 4; ++r) z[t][r] = tanh_fast(a[r]);
            }
        }
        #pragma unroll
        for (int t = 0; t < 2; ++t)
            #pragma unroll
            for (int r = 0; r < 4; ++r)
                XZ[swz(4 * g + r, 16 * t + c)] = bf16_rne(z[t][r]);

        // ---- 10 Euler steps ----
        for (int step = 0; step < 10; ++step) {
            short8 x0 = *reinterpret_cast<const short8*>(&XZ[swz(c, 8 * g)]);
            short8 x1 = *reinterpret_cast<const short8*>(&XZ[swz(c, 32 + 8 * g)]);
            #pragma unroll
            for (int t = 0; t < 4; ++t) {
                f32x4 a = {ob1b[t], ob1b[t], ob1b[t], ob1b[t]};
                a = mfma16(x0, ow1f[t][0], a);
                a = mfma16(x1, ow1f[t][1], a);
                #pragma unroll
                for (int r = 0; r < 4; ++r)
                    HB[swz(4 * g + r, 16 * t + c)] = bf16_rne(fmaxf(a[r], 0.0f));
            }
            short8 h0 = *reinterpret_cast<const short8*>(&HB[swz(c, 8 * g)]);
            short8 h1 = *reinterpret_cast<const short8*>(&HB[swz(c, 32 + 8 * g)]);
            #pragma unroll
            for (int t = 0; t < 2; ++t) {
                f32x4 a = {ob2b[t], ob2b[t], ob2b[t], ob2b[t]};
                a = mfma16(h0, ow2f[t][0], a);
                a = mfma16(h1, ow2f[t][1], a);
                #pragma unroll
                for (int r = 0; r < 4; ++r) z[t][r] += sv[r] * tanh_fast(a[r]);
            }
            #pragma unroll
            for (int t = 0; t < 2; ++t)
                #pragma unroll
                for (int r = 0; r < 4; ++r)
                    XZ[swz(4 * g + r, 16 * t + c)] = bf16_rne(z[t][r]);
        }

        // ---- heads: layer1 (mu||sigma hidden), tanh ----
        {
            short8 za = *reinterpret_cast<const short8*>(&XZ[swz(c, 8 * g)]);
            #pragma unroll
            for (int t = 0; t < 4; ++t) {
                f32x4 a = {hb1b[t], hb1b[t], hb1b[t], hb1b[t]};
                a = mfma16(za, hw1f[t], a);
                #pragma unroll
                for (int r = 0; r < 4; ++r)
                    HB[swz(4 * g + r, 16 * t + c)] = bf16_rne(tanh_fast(a[r]));
            }
            short8 h0 = *reinterpret_cast<const short8*>(&HB[swz(c, 8 * g)]);
            short8 h1 = *reinterpret_cast<const short8*>(&HB[swz(c, 32 + 8 * g)]);
            f32x4 a3 = {0.0f, 0.0f, 0.0f, 0.0f};
            a3 = mfma16(h0, hw2f[0], a3);
            a3 = mfma16(h1, hw2f[1], a3);
            if (c == 0) {
                #pragma unroll
                for (int r = 0; r < 4; ++r)
                    out[row0 + 4 * g + r] = a3[r] + mb2v;
            } else if (c == 1) {
                #pragma unroll
                for (int r = 0; r < 4; ++r) {
                    float v = a3[r] + sb2v;
                    out[rows + row0 + 4 * g + r] = fmaxf(v, 0.0f) +
                        0.69314718055994531f *
                        __builtin_log2f(1.0f + __builtin_exp2f(-fabsf(v) * 1.4426950408889634f));
                }
            }
        }
    }
}

extern "C" void kernel_launch(void* const* d_in, const int* in_sizes, int n_in,
                              void* d_out, int out_size, void* d_ws, size_t ws_size,
                              hipStream_t stream) {
    const float* dt  = (const float*)d_in[0];
    const float* x   = (const float*)d_in[1];
    const float* jw1 = (const float*)d_in[2];
    const float* jb1 = (const float*)d_in[3];
    const float* jw2 = (const float*)d_in[4];
    const float* jb2 = (const float*)d_in[5];
    const float* ow1 = (const float*)d_in[6];
    const float* ob1 = (const float*)d_in[7];
    const float* ow2 = (const float*)d_in[8];
    const float* ob2 = (const float*)d_in[9];
    const float* mw1 = (const float*)d_in[10];
    const float* mb1 = (const float*)d_in[11];
    const float* mw2 = (const float*)d_in[12];
    const float* mb2 = (const float*)d_in[13];
    const float* sw1 = (const float*)d_in[14];
    const float* sb1 = (const float*)d_in[15];
    const float* sw2 = (const float*)d_in[16];
    const float* sb2 = (const float*)d_in[17];
    float* out = (float*)d_out;

    const int rows = in_sizes[1] / 8;  // B*T
    const int grid = 768;              // 3 blocks/CU, 4 waves/block
    hipLaunchKernelGGL(latent_ode_mfma, dim3(grid), dim3(256), 0, stream,
                       dt, x, jw1, jb1, jw2, jb2, ow1, ob1, ow2, ob2,
                       mw1, mb1, mw2, mb2, sw1, sb1, sw2, sb2, out, rows);
}

// Round 3
// 237.011 us; speedup vs baseline: 5.4078x; 1.3097x over previous
//
#include <hip/hip_runtime.h>
#include <hip/hip_bf16.h>

// LatentODE round 3: transposed MFMA chain, K=16, zero LDS.
// Features along M, batch (16 rows) along N. Weights preloaded as A-fragments.
// D-layout (col=lane&15, row=4*(lane>>4)+r) == K=16 B-fragment layout
// (col=lane&15, k=4*(lane>>4)+j), so each layer's output feeds the next with
// only an in-register f32->bf16 pack. Biases folded in as a constant-1 K-row.

typedef __attribute__((ext_vector_type(4))) short short4v;
typedef __attribute__((ext_vector_type(4))) float f32x4;
typedef unsigned int uint_t;
typedef unsigned short ushort_t;

__device__ __forceinline__ uint_t fu(float f) { union { float f; uint_t u; } x; x.f = f; return x.u; }

__device__ __forceinline__ ushort_t bf16_rne(float f) {
    uint_t u = fu(f);
    u += 0x7FFFu + ((u >> 16) & 1u);
    return (ushort_t)(u >> 16);
}

__device__ __forceinline__ float tanh_fast(float v) {
    float e = __builtin_exp2f(v * 2.8853900817779268f);
    return 1.0f - 2.0f * __builtin_amdgcn_rcpf(e + 1.0f);
}

// pack 4 f32 -> 4 bf16 (round-half-up) via v_perm_b32: 6 VALU ops total
__device__ __forceinline__ short4v pack4(f32x4 v) {
    uint_t lo = __builtin_amdgcn_perm(fu(v[1]) + 0x8000u, fu(v[0]) + 0x8000u, 0x07060302u);
    uint_t hi = __builtin_amdgcn_perm(fu(v[3]) + 0x8000u, fu(v[2]) + 0x8000u, 0x07060302u);
    union { uint_t u[2]; short4v s; } p;
    p.u[0] = lo; p.u[1] = hi;
    return p.s;
}

__device__ __forceinline__ f32x4 mfma_k16(short4v a, short4v b, f32x4 c) {
#if __has_builtin(__builtin_amdgcn_mfma_f32_16x16x16bf16_1k)
    return __builtin_amdgcn_mfma_f32_16x16x16bf16_1k(a, b, c, 0, 0, 0);
#elif __has_builtin(__builtin_amdgcn_mfma_f32_16x16x16_bf16)
    return __builtin_amdgcn_mfma_f32_16x16x16_bf16(a, b, c, 0, 0, 0);
#else
    f32x4 d;
    asm volatile("v_mfma_f32_16x16x16_bf16 %0, %1, %2, %3"
                 : "=v"(d) : "v"(a), "v"(b), "v"(c));
    return d;
#endif
}

// A-fragment of W^T tile: lane (g,c): row m = 16t+c, k = koff+4g+j
template <typename F>
__device__ __forceinline__ short4v load_afrag(F getv, int c, int g, int koff, int t) {
    short4v r;
    #pragma unroll
    for (int j = 0; j < 4; ++j)
        r[j] = (short)bf16_rne(getv(koff + 4 * g + j, 16 * t + c));
    return r;
}

__global__ __launch_bounds__(256, 3) void latent_ode_t(
    const float* __restrict__ dt, const float* __restrict__ x,
    const float* __restrict__ jw1, const float* __restrict__ jb1,
    const float* __restrict__ jw2, const float* __restrict__ jb2,
    const float* __restrict__ ow1, const float* __restrict__ ob1,
    const float* __restrict__ ow2, const float* __restrict__ ob2,
    const float* __restrict__ mw1, const float* __restrict__ mb1,
    const float* __restrict__ mw2, const float* __restrict__ mb2,
    const float* __restrict__ sw1, const float* __restrict__ sb1,
    const float* __restrict__ sw2, const float* __restrict__ sb2,
    float* __restrict__ out, int rows)
{
    const int tid = threadIdx.x;
    const int lane = tid & 63;
    const int g = lane >> 4, c = lane & 15;

    // ---- weight element getters (bias folded at the padded K-row) ----
    auto jw1e = [&](int k, int n) -> float {
        if (n >= 50) return 0.f;
        if (k < 8) return jw1[k * 50 + n];
        if (k == 8) return jb1[n];
        return 0.f;
    };
    auto jw2e = [&](int k, int n) -> float {
        if (k < 50) return jw2[k * 32 + n];
        if (k == 50) return jb2[n];
        return 0.f;
    };
    auto ow1e = [&](int k, int n) -> float {
        if (n >= 50) return 0.f;
        if (k < 40) return ow1[k * 50 + n];
        if (k == 40) return ob1[n];
        return 0.f;
    };
    auto ow2e = [&](int k, int n) -> float {
        if (k < 50) return ow2[k * 32 + n];
        if (k == 50) return ob2[n];
        return 0.f;
    };
    auto hw1e = [&](int k, int n) -> float {
        const float* w = (n < 32) ? mw1 : sw1;
        const float* b = (n < 32) ? mb1 : sb1;
        int nn = n & 31;
        if (k < 32) return w[k * 32 + nn];
        if (k == 32) return b[nn];
        return 0.f;
    };
    auto hw2e = [&](int k, int n) -> float {
        if (n == 0) return (k < 32) ? mw2[k] : 0.f;
        if (n == 1) return (k >= 32 && k < 64) ? sw2[k - 32] : 0.f;
        return 0.f;
    };

    // ---- preload all weight A-fragments into registers (96 VGPRs) ----
    short4v jw1f[4], jw2f[2][4], ow1f[4][3], ow2f[2][4], hw1f[4][3], hw2f[4];
    #pragma unroll
    for (int t = 0; t < 4; ++t) {
        jw1f[t] = load_afrag(jw1e, c, g, 0, t);
        #pragma unroll
        for (int ks = 0; ks < 3; ++ks) {
            ow1f[t][ks] = load_afrag(ow1e, c, g, 16 * ks, t);
            hw1f[t][ks] = load_afrag(hw1e, c, g, 16 * ks, t);
        }
    }
    #pragma unroll
    for (int t = 0; t < 2; ++t)
        #pragma unroll
        for (int ks = 0; ks < 4; ++ks) {
            jw2f[t][ks] = load_afrag(jw2e, c, g, 16 * ks, t);
            ow2f[t][ks] = load_afrag(ow2e, c, g, 16 * ks, t);
        }
    #pragma unroll
    for (int ks = 0; ks < 4; ++ks)
        hw2f[ks] = load_afrag(hw2e, c, g, 16 * ks, 0);

    const float mb2v = mb2[0], sb2v = sb2[0];
    const short ONE = (short)0x3F80;  // bf16(1.0)

    // constant-1 fragment for head-L1 bias K-slice (feature 32 -> g=0,j=0)
    short4v onef = {0, 0, 0, 0};
    if (g == 0) onef[0] = ONE;

    const int ntiles = rows >> 4;
    const int nwaves = (gridDim.x * blockDim.x) >> 6;
    const int wgid = (blockIdx.x * blockDim.x + tid) >> 6;

    for (int tile = wgid; tile < ntiles; tile += nwaves) {
        const int row0 = tile << 4;

        // x B-fragment: features 0..7 = x, feature 8 = 1 (bias row).
        // Serves jump-L1 (ks=0) and ODE-L1 (ks=2, features 32..39 + bias@40).
        short4v xb = {0, 0, 0, 0};
        if (g < 2) {
            const float4 xv = *reinterpret_cast<const float4*>(
                &x[(size_t)(row0 + c) * 8 + 4 * g]);
            f32x4 q = {xv.x, xv.y, xv.z, xv.w};
            xb = pack4(q);
        } else if (g == 2) {
            xb[0] = ONE;
        }
        const float2 dv = *reinterpret_cast<const float2*>(&dt[2 * (size_t)(row0 + c)]);
        const float sv = (dv.y - dv.x) * (1.0f / 240.0f);

        // ---- jumpNN L1: h = tanh(jw1^T x + jb1), 4 tiles ----
        short4v hf[4];
        #pragma unroll
        for (int t = 0; t < 4; ++t) {
            f32x4 a = {0.f, 0.f, 0.f, 0.f};
            a = mfma_k16(jw1f[t], xb, a);
            f32x4 v;
            #pragma unroll
            for (int r = 0; r < 4; ++r) v[r] = tanh_fast(a[r]);
            hf[t] = pack4(v);
        }
        if (g == 0) hf[3][2] = ONE;  // bias feature 50 for L2

        // ---- jumpNN L2: z0 = tanh(jw2^T h + jb2), 2 tiles ----
        f32x4 zm[2];
        short4v zf[2];
        #pragma unroll
        for (int t = 0; t < 2; ++t) {
            f32x4 a = {0.f, 0.f, 0.f, 0.f};
            #pragma unroll
            for (int ks = 0; ks < 4; ++ks) a = mfma_k16(jw2f[t][ks], hf[ks], a);
            #pragma unroll
            for (int r = 0; r < 4; ++r) zm[t][r] = tanh_fast(a[r]);
            zf[t] = pack4(zm[t]);
        }

        // ---- 10 Euler steps ----
        #pragma unroll 1
        for (int step = 0; step < 10; ++step) {
            #pragma unroll
            for (int t = 0; t < 4; ++t) {
                f32x4 a = {0.f, 0.f, 0.f, 0.f};
                a = mfma_k16(ow1f[t][0], zf[0], a);
                a = mfma_k16(ow1f[t][1], zf[1], a);
                a = mfma_k16(ow1f[t][2], xb, a);
                f32x4 v;
                #pragma unroll
                for (int r = 0; r < 4; ++r) v[r] = fmaxf(a[r], 0.0f);
                hf[t] = pack4(v);
            }
            if (g == 0) hf[3][2] = ONE;  // bias feature 50
            #pragma unroll
            for (int t = 0; t < 2; ++t) {
                f32x4 a = {0.f, 0.f, 0.f, 0.f};
                #pragma unroll
                for (int ks = 0; ks < 4; ++ks) a = mfma_k16(ow2f[t][ks], hf[ks], a);
                #pragma unroll
                for (int r = 0; r < 4; ++r) zm[t][r] += sv * tanh_fast(a[r]);
                zf[t] = pack4(zm[t]);
            }
        }

        // ---- heads L1: [tanh(mw1^T z + mb1); tanh(sw1^T z + sb1)], 4 tiles ----
        short4v hh[4];
        #pragma unroll
        for (int t = 0; t < 4; ++t) {
            f32x4 a = {0.f, 0.f, 0.f, 0.f};
            a = mfma_k16(hw1f[t][0], zf[0], a);
            a = mfma_k16(hw1f[t][1], zf[1], a);
            a = mfma_k16(hw1f[t][2], onef, a);
            f32x4 v;
            #pragma unroll
            for (int r = 0; r < 4; ++r) v[r] = tanh_fast(a[r]);
            hh[t] = pack4(v);
        }
        // ---- heads L2: row0 = mu, row1 = sigma ----
        f32x4 o = {0.f, 0.f, 0.f, 0.f};
        #pragma unroll
        for (int ks = 0; ks < 4; ++ks) o = mfma_k16(hw2f[ks], hh[ks], o);

        if (lane < 16) {
            out[row0 + c] = o[0] + mb2v;
            float v2 = o[1] + sb2v;
            out[rows + row0 + c] = fmaxf(v2, 0.0f) +
                0.69314718055994531f *
                __builtin_log2f(1.0f + __builtin_exp2f(-fabsf(v2) * 1.4426950408889634f));
        }
    }
}

extern "C" void kernel_launch(void* const* d_in, const int* in_sizes, int n_in,
                              void* d_out, int out_size, void* d_ws, size_t ws_size,
                              hipStream_t stream) {
    const float* dt  = (const float*)d_in[0];
    const float* x   = (const float*)d_in[1];
    const float* jw1 = (const float*)d_in[2];
    const float* jb1 = (const float*)d_in[3];
    const float* jw2 = (const float*)d_in[4];
    const float* jb2 = (const float*)d_in[5];
    const float* ow1 = (const float*)d_in[6];
    const float* ob1 = (const float*)d_in[7];
    const float* ow2 = (const float*)d_in[8];
    const float* ob2 = (const float*)d_in[9];
    const float* mw1 = (const float*)d_in[10];
    const float* mb1 = (const float*)d_in[11];
    const float* mw2 = (const float*)d_in[12];
    const float* mb2 = (const float*)d_in[13];
    const float* sw1 = (const float*)d_in[14];
    const float* sb1 = (const float*)d_in[15];
    const float* sw2 = (const float*)d_in[16];
    const float* sb2 = (const float*)d_in[17];
    float* out = (float*)d_out;

    const int rows = in_sizes[1] / 8;  // B*T = 819200
    const int grid = 768;              // 3 blocks/CU resident, 4 waves/block
    hipLaunchKernelGGL(latent_ode_t, dim3(grid), dim3(256), 0, stream,
                       dt, x, jw1, jb1, jw2, jb2, ow1, ob1, ow2, ob2,
                       mw1, mb1, mw2, mb2, sw1, sb1, sw2, sb2, out, rows);
}